// Round 5
// baseline (1050.444 us; speedup 1.0000x reference)
//
#include <hip/hip_runtime.h>
#include <math.h>
#include <stdint.h>

typedef unsigned short u16;
typedef __attribute__((ext_vector_type(8))) short short8;   // 8 bf16 (4 VGPRs)
typedef __attribute__((ext_vector_type(4))) float floatx4;  // MFMA acc

__device__ __forceinline__ float b2f(u16 u){
  union{unsigned int i; float f;} v; v.i = ((unsigned int)u)<<16; return v.f;
}
__device__ __forceinline__ u16 f2b(float f){
  union{unsigned int i; float f;} v; v.f = f;
  unsigned int r = (v.i + 0x7FFFu + ((v.i>>16)&1u))>>16;
  return (u16)r;
}
__device__ __forceinline__ unsigned int pk2(float a, float b){
  return (unsigned int)f2b(a) | ((unsigned int)f2b(b)<<16);
}
// dual-dtype external scalar load: isb=1 -> bf16(u16), isb=0 -> float32
__device__ __forceinline__ float ldx(const void* p, size_t i, int isb){
  return isb ? b2f(((const u16*)p)[i]) : ((const float*)p)[i];
}

// dtype sniffer: bf16 N(0,1) data has exponent field in [110,139] for ~all
// even-indexed u16s; f32 low-mantissa halves are uniform (~12% in window).
__global__ void k_sniff(const void* __restrict__ X, int* __restrict__ flag)
{
  __shared__ int cnt;
  if (threadIdx.x==0) cnt = 0;
  __syncthreads();
  int c = 0;
  for (int t = threadIdx.x; t < 512; t += 256){
    unsigned int u = ((const u16*)X)[2*t];
    int e = (u >> 7) & 0xFF;
    if (e >= 110 && e <= 139) c++;
  }
  atomicAdd(&cnt, c);
  __syncthreads();
  if (threadIdx.x==0) *flag = (cnt > 300) ? 1 : 0;
}

__global__ __launch_bounds__(256) void k_zero(float* __restrict__ p, int n)
{
  int i = blockIdx.x*256 + threadIdx.x;
  if (i < n) p[i] = 0.f;
}
__global__ __launch_bounds__(256) void k_zero_int(int* __restrict__ p, int n)
{
  int i = blockIdx.x*256 + threadIdx.x;
  if (i < n) p[i] = 0;
}

// CSR build: histogram of dst, block-scan to rowptr (+fill copy), scatter.
__global__ __launch_bounds__(256) void k_hist(
    const int* __restrict__ ei, int* __restrict__ counts, int E)
{
  int e = blockIdx.x*256 + threadIdx.x;
  if (e < E) atomicAdd(&counts[ei[e]], 1);
}
__global__ __launch_bounds__(256) void k_scan(
    const int* __restrict__ counts, int* __restrict__ rowptr,
    int* __restrict__ fill, int N)
{
  __shared__ int sm[256];
  __shared__ int carry;
  int tid = threadIdx.x;
  if (tid == 0) carry = 0;
  __syncthreads();
  for (int base = 0; base < N; base += 256){
    int v = (base+tid < N) ? counts[base+tid] : 0;
    sm[tid] = v;
    __syncthreads();
    for (int off=1; off<256; off<<=1){
      int t = (tid >= off) ? sm[tid-off] : 0;
      __syncthreads();
      sm[tid] += t;
      __syncthreads();
    }
    int excl = carry + sm[tid] - v;
    if (base+tid < N){ rowptr[base+tid] = excl; fill[base+tid] = excl; }
    __syncthreads();
    if (tid == 0) carry += sm[255];
    __syncthreads();
  }
  if (tid == 0) rowptr[N] = carry;
}
__global__ __launch_bounds__(256) void k_scatter(
    const int* __restrict__ ei, int* __restrict__ fill,
    int* __restrict__ eorder, int E)
{
  int e = blockIdx.x*256 + threadIdx.x;
  if (e >= E) return;
  int d = ei[e];
  int pos = atomicAdd(&fill[d], 1);
  eorder[pos] = e;
}

// normalize X, decompose into 10 independent components (bf16)
__global__ __launch_bounds__(256) void k_decompose(
    const void* __restrict__ X, u16* __restrict__ Di, u16* __restrict__ Da,
    u16* __restrict__ Ds, int NH, const int* __restrict__ dflag)
{
  int tid = blockIdx.x*256 + threadIdx.x;
  if (tid >= NH) return;
  int isb = *dflag;
  int n = tid >> 7, k = tid & 127;
  float x[9]; float nrm = 0.f;
#pragma unroll
  for (int i=0;i<9;i++){ x[i]=ldx(X,(size_t)tid*9+i,isb); nrm += x[i]*x[i]; }
  float inv = 1.0f/(nrm+1.0f);
#pragma unroll
  for (int i=0;i<9;i++) x[i]*=inv;
  float i0 = (x[0]+x[4]+x[8])*(1.0f/3.0f);
  Di[tid] = f2b(i0);
  size_t ab = ((size_t)n*3)*128 + k;
  Da[ab      ] = f2b(0.5f*(x[1]-x[3]));
  Da[ab + 128] = f2b(0.5f*(x[2]-x[6]));
  Da[ab + 256] = f2b(0.5f*(x[5]-x[7]));
  size_t sb = ((size_t)n*6)*128 + k;
  Ds[sb      ] = f2b(x[0]-i0);
  Ds[sb + 128] = f2b(0.5f*(x[1]+x[3]));
  Ds[sb + 256] = f2b(0.5f*(x[2]+x[6]));
  Ds[sb + 384] = f2b(x[4]-i0);
  Ds[sb + 512] = f2b(0.5f*(x[5]+x[7]));
  Ds[sb + 640] = f2b(x[8]-i0);
}

// ---------------------------------------------------------------------------
// MFMA GEMM: C[M,Ncol](bf16) = A[M,K] * B[Ncol,K]^T  (+bias, silu, rowscale)
// 128x128 tile, 4 waves (2x2 of 64x64), BK=32, mfma_f32_16x16x32_bf16.
// Fragment-major LDS (one uint4 per lane-frag), register prefetch.
// flags: 1=silu, 2=cutoff-rowscale via ew[rowidx[ridx0+row]],
//        4=permute B rows/bias cols (i&127)*3+(i>>7), 8=gather A rows via rowidx
// Requires: Ncol %128==0, K %32==0.
// ---------------------------------------------------------------------------
__global__ __launch_bounds__(256) void k_mfma_gemm(
    const void* __restrict__ A, size_t aoff, const int* __restrict__ rowidx, int ridx0,
    const void* __restrict__ Bw, size_t boff,
    const void* __restrict__ bias, const void* __restrict__ ew,
    u16* __restrict__ C, int M, int Ncol, int K, int flags,
    int aext, int bext, const int* __restrict__ dflag)
{
  __shared__ uint4 AsF[512];   // frag = (mblk*64 + q*16 + l15), mblk=row>>4
  __shared__ uint4 BsF[512];
  int isb = *dflag;
  int isbA = aext ? isb : 1;
  int isbB = bext ? isb : 1;
  int tid = threadIdx.x;
  int lane = tid & 63, l15 = lane & 15, q = lane >> 4;
  int wid = tid >> 6, wm = wid & 1, wn = wid >> 1;
  int n0 = blockIdx.x * 128, m0 = blockIdx.y * 128;
  // staging role: row r (0..127), k-halves cs in {0,16}
  int r = tid >> 1, cs = (tid & 1) * 16;
  int f0 = (r>>4)*64 + (cs>>3)*16 + (r&15);   // frag idx for k=cs..cs+7
  int f1 = f0 + 16;                            // frag idx for k=cs+8..cs+15

  floatx4 acc[4][4];
#pragma unroll
  for (int i=0;i<4;i++)
#pragma unroll
    for (int j=0;j<4;j++) acc[i][j] = (floatx4)0.f;

  long arow = -1;
  {
    int gm = m0 + r;
    if (gm < M) arow = (flags & 8) ? (long)rowidx[ridx0 + gm] : (long)gm;
  }
  int brow_g = n0 + r;
  int bsrc = (flags & 4) ? ((brow_g & 127)*3 + (brow_g >> 7)) : brow_g;

  uint4 ga0, ga1, gb0, gb1;
  auto ldtile = [&](int k0){
    if (arow >= 0){
      size_t base = aoff + (size_t)arow*K + k0 + cs;
      if (isbA){
        const uint4* p = reinterpret_cast<const uint4*>((const u16*)A + base);
        ga0 = p[0]; ga1 = p[1];
      } else {
        const float4* p = reinterpret_cast<const float4*>((const float*)A + base);
        float4 v0=p[0], v1=p[1], v2=p[2], v3=p[3];
        ga0 = make_uint4(pk2(v0.x,v0.y), pk2(v0.z,v0.w), pk2(v1.x,v1.y), pk2(v1.z,v1.w));
        ga1 = make_uint4(pk2(v2.x,v2.y), pk2(v2.z,v2.w), pk2(v3.x,v3.y), pk2(v3.z,v3.w));
      }
    } else { ga0 = make_uint4(0,0,0,0); ga1 = ga0; }
    {
      size_t base = boff + (size_t)bsrc*K + k0 + cs;
      if (isbB){
        const uint4* p = reinterpret_cast<const uint4*>((const u16*)Bw + base);
        gb0 = p[0]; gb1 = p[1];
      } else {
        const float4* p = reinterpret_cast<const float4*>((const float*)Bw + base);
        float4 v0=p[0], v1=p[1], v2=p[2], v3=p[3];
        gb0 = make_uint4(pk2(v0.x,v0.y), pk2(v0.z,v0.w), pk2(v1.x,v1.y), pk2(v1.z,v1.w));
        gb1 = make_uint4(pk2(v2.x,v2.y), pk2(v2.z,v2.w), pk2(v3.x,v3.y), pk2(v3.z,v3.w));
      }
    }
  };

  ldtile(0);
  for (int k0 = 0; k0 < K; k0 += 32){
    __syncthreads();            // previous iteration's frag reads done
    AsF[f0] = ga0; AsF[f1] = ga1;
    BsF[f0] = gb0; BsF[f1] = gb1;
    __syncthreads();
    if (k0 + 32 < K) ldtile(k0 + 32);   // prefetch overlaps MFMA below
    short8 av[4], bv[4];
#pragma unroll
    for (int mt=0; mt<4; mt++)
      av[mt] = *reinterpret_cast<const short8*>(&AsF[(wm*4 + mt)*64 + lane]);
#pragma unroll
    for (int nt=0; nt<4; nt++)
      bv[nt] = *reinterpret_cast<const short8*>(&BsF[(wn*4 + nt)*64 + lane]);
#pragma unroll
    for (int mt=0; mt<4; mt++)
#pragma unroll
      for (int nt=0; nt<4; nt++)
        acc[mt][nt] = __builtin_amdgcn_mfma_f32_16x16x32_bf16(av[mt], bv[nt], acc[mt][nt], 0, 0, 0);
  }

  float biasv[4];
#pragma unroll
  for (int nt=0; nt<4; nt++){
    int col = n0 + wn*64 + nt*16 + l15;
    int bcol = (flags & 4) ? ((col & 127)*3 + (col >> 7)) : col;
    biasv[nt] = bias ? ldx(bias, bcol, isbB) : 0.f;
  }
#pragma unroll
  for (int mt=0; mt<4; mt++){
#pragma unroll
    for (int reg=0; reg<4; reg++){
      int row = m0 + wm*64 + mt*16 + q*4 + reg;
      if (row >= M) continue;
      float rs = 1.0f;
      if (flags & 2){
        int edge = rowidx[ridx0 + row];
        float w = ldx(ew, edge, isb);
        rs = (w < 4.5f) ? 0.5f*(cosf(w*0.6981317007977318f) + 1.0f) : 0.0f;
      }
#pragma unroll
      for (int nt=0; nt<4; nt++){
        int col = n0 + wn*64 + nt*16 + l15;
        float t = acc[mt][nt][reg] + biasv[nt];
        if (flags & 1) t = t / (1.0f + expf(-t));
        C[(size_t)row*Ncol + col] = f2b(t*rs);
      }
    }
  }
}

// ---------------------------------------------------------------------------
// Gather message passing: block per dst node, 128 threads = channels.
// Edges sorted by dst; chunk [c0,c1). ea chunk layout [ec][3][128] (permB).
// Non-atomic msg += (one block per node; chunks sequential on stream).
// msg layout [9][NH] f32 (coalesced).
// ---------------------------------------------------------------------------
__global__ __launch_bounds__(128) void k_gather(
    const int* __restrict__ rowptr, const int* __restrict__ eorder,
    const int* __restrict__ ei, int E, int c0, int c1,
    const u16* __restrict__ ea,
    const u16* __restrict__ Pi, const u16* __restrict__ Pa,
    const u16* __restrict__ Ps, const void* __restrict__ b1,
    float* __restrict__ msg, int NH, const int* __restrict__ dflag)
{
  int n = blockIdx.x;
  int lo = rowptr[n], hi = rowptr[n+1];
  if (lo < c0) lo = c0;
  if (hi > c1) hi = c1;
  if (lo >= hi) return;
  int isb = *dflag;
  int c = threadIdx.x;
  float b0 = ldx(b1,c,isb), b1f = ldx(b1,128+c,isb), b2v = ldx(b1,256+c,isb);
  float m[9];
#pragma unroll
  for (int i=0;i<9;i++) m[i]=0.f;
  for (int idx = lo; idx < hi; idx++){
    int e = eorder[idx];
    int src = ei[E + e];
    const u16* er = ea + (size_t)(idx - c0)*384;
    float e0f = b2f(er[c]), e1f = b2f(er[128+c]), e2f = b2f(er[256+c]);
    float i1 = b2f(Pi[(size_t)src*128 + c]);
    size_t ab = (size_t)src*384 + c;
    float a0 = b2f(Pa[ab]), a1 = b2f(Pa[ab+128]), a2 = b2f(Pa[ab+256]);
    size_t sb = (size_t)src*768 + c;
    float s0 = b2f(Ps[sb]),     s1 = b2f(Ps[sb+128]), s2 = b2f(Ps[sb+256]);
    float s3 = b2f(Ps[sb+384]), s4 = b2f(Ps[sb+512]), s5 = b2f(Ps[sb+640]);
    float bb = e0f*b0 + e1f*b1f + e2f*b2v;
    float t0 = e0f*i1;
    m[0] += t0 + e2f*s0 + bb;
    m[1] += e1f*a0 + e2f*s1 + bb;
    m[2] += e1f*a1 + e2f*s2 + bb;
    m[3] += -e1f*a0 + e2f*s1 + bb;
    m[4] += t0 + e2f*s3 + bb;
    m[5] += e1f*a2 + e2f*s4 + bb;
    m[6] += -e1f*a1 + e2f*s2 + bb;
    m[7] += -e1f*a2 + e2f*s4 + bb;
    m[8] += t0 + e2f*s5 + bb;
  }
  size_t o = (size_t)n*128 + c;
#pragma unroll
  for (int i=0;i<9;i++) msg[(size_t)i*NH + o] += m[i];
}

// Update: F = msg*Y + Y*msg, renormalize, decompose -> D2 (bf16)
__global__ __launch_bounds__(256) void k_update(
    const float* __restrict__ msg, const u16* __restrict__ Pi,
    const u16* __restrict__ Pa, const u16* __restrict__ Ps,
    const void* __restrict__ b1,
    u16* __restrict__ D2i, u16* __restrict__ D2a, u16* __restrict__ D2s,
    int NH, const int* __restrict__ dflag)
{
  int tid = blockIdx.x*256 + threadIdx.x;
  if (tid >= NH) return;
  int isb = *dflag;
  int n = tid >> 7, c = tid & 127;
  float Mx[9];
#pragma unroll
  for (int i=0;i<9;i++) Mx[i] = msg[(size_t)i*NH + tid];
  float i1 = b2f(Pi[tid]);
  size_t ab = ((size_t)n*3)*128 + c;
  float a0 = b2f(Pa[ab]), a1 = b2f(Pa[ab+128]), a2 = b2f(Pa[ab+256]);
  size_t sb = ((size_t)n*6)*128 + c;
  float s0 = b2f(Ps[sb]),     s1 = b2f(Ps[sb+128]), s2 = b2f(Ps[sb+256]);
  float s3 = b2f(Ps[sb+384]), s4 = b2f(Ps[sb+512]), s5 = b2f(Ps[sb+640]);
  float B = ldx(b1,c,isb) + ldx(b1,128+c,isb) + ldx(b1,256+c,isb);
  float Y[9];
  Y[0]= i1+s0+B; Y[1]= a0+s1+B; Y[2]= a1+s2+B;
  Y[3]=-a0+s1+B; Y[4]= i1+s3+B; Y[5]= a2+s4+B;
  Y[6]=-a1+s2+B; Y[7]=-a2+s4+B; Y[8]= i1+s5+B;
  float F[9];
#pragma unroll
  for (int i=0;i<3;i++)
#pragma unroll
    for (int j=0;j<3;j++){
      float acc = 0.f;
#pragma unroll
      for (int t=0;t<3;t++)
        acc += Mx[i*3+t]*Y[t*3+j] + Y[i*3+t]*Mx[t*3+j];
      F[i*3+j] = acc;
    }
  float nrm = 0.f;
#pragma unroll
  for (int i=0;i<9;i++) nrm += F[i]*F[i];
  float inv = 1.0f/(nrm+1.0f);
  float i2 = (F[0]+F[4]+F[8])*(1.0f/3.0f);
  D2i[tid] = f2b(i2*inv);
  D2a[ab      ] = f2b(0.5f*(F[1]-F[3])*inv);
  D2a[ab + 128] = f2b(0.5f*(F[2]-F[6])*inv);
  D2a[ab + 256] = f2b(0.5f*(F[5]-F[7])*inv);
  D2s[sb      ] = f2b((F[0]-i2)*inv);
  D2s[sb + 128] = f2b(0.5f*(F[1]+F[3])*inv);
  D2s[sb + 256] = f2b(0.5f*(F[2]+F[6])*inv);
  D2s[sb + 384] = f2b((F[4]-i2)*inv);
  D2s[sb + 512] = f2b(0.5f*(F[5]+F[7])*inv);
  D2s[sb + 640] = f2b((F[8]-i2)*inv);
}

// Final: dX from P2 + b3; out = Xn + dX + dX*dX (dual-dtype out)
__global__ __launch_bounds__(256) void k_final(
    const void* __restrict__ X, const u16* __restrict__ P2i,
    const u16* __restrict__ P2a, const u16* __restrict__ P2s,
    const void* __restrict__ b3, void* __restrict__ out, int NH,
    const int* __restrict__ dflag)
{
  int tid = blockIdx.x*256 + threadIdx.x;
  if (tid >= NH) return;
  int isb = *dflag;
  int n = tid >> 7, c = tid & 127;
  float i1 = b2f(P2i[tid]);
  size_t ab = ((size_t)n*3)*128 + c;
  float a0 = b2f(P2a[ab]), a1 = b2f(P2a[ab+128]), a2 = b2f(P2a[ab+256]);
  size_t sb = ((size_t)n*6)*128 + c;
  float s0 = b2f(P2s[sb]),     s1 = b2f(P2s[sb+128]), s2 = b2f(P2s[sb+256]);
  float s3 = b2f(P2s[sb+384]), s4 = b2f(P2s[sb+512]), s5 = b2f(P2s[sb+640]);
  float B = ldx(b3,c,isb) + ldx(b3,128+c,isb) + ldx(b3,256+c,isb);
  float dX[9];
  dX[0]= i1+s0+B; dX[1]= a0+s1+B; dX[2]= a1+s2+B;
  dX[3]=-a0+s1+B; dX[4]= i1+s3+B; dX[5]= a2+s4+B;
  dX[6]=-a1+s2+B; dX[7]=-a2+s4+B; dX[8]= i1+s5+B;

  float x[9]; float nrm = 0.f;
#pragma unroll
  for (int i=0;i<9;i++){ x[i]=ldx(X,(size_t)tid*9+i,isb); nrm += x[i]*x[i]; }
  float inv = 1.0f/(nrm+1.0f);

#pragma unroll
  for (int i=0;i<3;i++)
#pragma unroll
    for (int j=0;j<3;j++){
      float acc = 0.f;
#pragma unroll
      for (int t=0;t<3;t++) acc += dX[i*3+t]*dX[t*3+j];
      float v = x[i*3+j]*inv + dX[i*3+j] + acc;
      size_t oi = (size_t)tid*9 + i*3 + j;
      if (isb) ((u16*)out)[oi] = f2b(v);
      else     ((float*)out)[oi] = v;
    }
}

extern "C" void kernel_launch(void* const* d_in, const int* in_sizes, int n_in,
                              void* d_out, int out_size, void* d_ws, size_t ws_size,
                              hipStream_t stream)
{
  const void* X    = d_in[0];
  const int*  ei   = (const int*)d_in[1];
  const void* ew   = d_in[2];
  const void* eatt = d_in[3];
  const void* W1   = d_in[4];
  const void* b1   = d_in[5];
  const void* W2a  = d_in[6];
  const void* b2a  = d_in[7];
  const void* W2b  = d_in[8];
  const void* b2b  = d_in[9];
  const void* W2c  = d_in[10];
  const void* b2c  = d_in[11];
  const void* W3   = d_in[12];
  const void* b3   = d_in[13];

  const int NH = in_sizes[0]/9;   // 20001*128
  const int E  = in_sizes[2];     // 200000
  const int N  = NH/128;

  auto aln = [](size_t x){ return (x + 255) & ~(size_t)255; };
  char* ws = (char*)d_ws;
  size_t off = 0;
  size_t o_flag = off; off += 256;
  size_t o_msg  = off; off += aln((size_t)NH*9*4);
  size_t o_Di   = off; off += aln((size_t)NH*2);
  size_t o_Da   = off; off += aln((size_t)NH*6);
  size_t o_Ds   = off; off += aln((size_t)NH*12);
  size_t o_Pi   = off; off += aln((size_t)NH*2);
  size_t o_Pa   = off; off += aln((size_t)NH*6);
  size_t o_Ps   = off; off += aln((size_t)NH*12);
  size_t o_cnt  = off; off += aln((size_t)N*4);
  size_t o_rp   = off; off += aln((size_t)(N+1)*4);
  size_t o_fill = off; off += aln((size_t)N*4);
  size_t o_eord = off; off += aln((size_t)E*4);
  size_t persistent = off;

  // Per-edge chunk footprint: h1(256B)+h2(512B)+ea(768B) = 1536B
  int EC;
  {
    size_t avail = (ws_size > persistent + 4096) ? (ws_size - persistent - 4096) : 0;
    size_t ecmax = avail / 1536;
    if (ecmax > (size_t)E) ecmax = (size_t)E;
    EC = (int)(ecmax & ~(size_t)1023);
    if (EC < 1024) EC = 1024;
  }
  size_t o_h1 = persistent;
  size_t o_h2 = o_h1 + aln((size_t)EC*256);
  size_t o_ea = o_h2 + aln((size_t)EC*512);
  (void)n_in; (void)out_size;

  int* dflag = (int*)(ws + o_flag);
  u16* Di = (u16*)(ws + o_Di);
  u16* Da = (u16*)(ws + o_Da);
  u16* Ds = (u16*)(ws + o_Ds);
  u16* Pi = (u16*)(ws + o_Pi);
  u16* Pa = (u16*)(ws + o_Pa);
  u16* Ps = (u16*)(ws + o_Ps);
  float* msg = (float*)(ws + o_msg);
  int* counts = (int*)(ws + o_cnt);
  int* rowptr = (int*)(ws + o_rp);
  int* fill   = (int*)(ws + o_fill);
  int* eorder = (int*)(ws + o_eord);
  u16* h1 = (u16*)(ws + o_h1);
  u16* h2 = (u16*)(ws + o_h2);
  u16* ea = (u16*)(ws + o_ea);

  dim3 blk(256);
  auto gemm = [&](const void* A, size_t aoff, const int* ridx, int ridx0,
                  const void* Bw, size_t boff, const void* bias, const void* ewp,
                  u16* C, int M, int Ncol, int K, int flags, int aext, int bext){
    dim3 grid(Ncol/128, (M+127)/128);
    k_mfma_gemm<<<grid, blk, 0, stream>>>(A, aoff, ridx, ridx0, Bw, boff, bias, ewp,
                                          C, M, Ncol, K, flags, aext, bext, dflag);
  };

  // 0. sniff dtype
  k_sniff<<<1, blk, 0, stream>>>(X, dflag);
  // 1. decompose
  k_decompose<<<(NH+255)/256, blk, 0, stream>>>(X, Di, Da, Ds, NH, dflag);
  // 2. node linears (W1) -> P components
  gemm(Di, 0, nullptr, 0, W1, 0,     nullptr, nullptr, Pi, N,   128, 128, 0, 0, 1);
  gemm(Da, 0, nullptr, 0, W1, 16384, nullptr, nullptr, Pa, 3*N, 128, 128, 0, 0, 1);
  gemm(Ds, 0, nullptr, 0, W1, 32768, nullptr, nullptr, Ps, 6*N, 128, 128, 0, 0, 1);
  // 3. zero msg accumulator; build CSR (sort edges by dst)
  k_zero<<<((NH*9)+255)/256, blk, 0, stream>>>(msg, NH*9);
  k_zero_int<<<(N+255)/256, blk, 0, stream>>>(counts, N);
  k_hist<<<(E+255)/256, blk, 0, stream>>>(ei, counts, E);
  k_scan<<<1, blk, 0, stream>>>(counts, rowptr, fill, N);
  k_scatter<<<(E+255)/256, blk, 0, stream>>>(ei, fill, eorder, E);
  // 4. edge MLP (dst-sorted order) + gather message passing, chunked
  for (int c0 = 0; c0 < E; c0 += EC){
    int ec = E - c0; if (ec > EC) ec = EC;
    gemm(eatt, 0, eorder, c0, W2a, 0, b2a, nullptr, h1, ec, 128, 64,  1|8, 1, 1);
    gemm(h1, 0, nullptr, 0,   W2b, 0, b2b, nullptr, h2, ec, 256, 128, 1, 0, 1);
    gemm(h2, 0, eorder, c0,   W2c, 0, b2c, ew,      ea, ec, 384, 256, 1|2|4, 0, 1);
    k_gather<<<N, dim3(128), 0, stream>>>(rowptr, eorder, ei, E, c0, c0+ec,
                                          ea, Pi, Pa, Ps, b1, msg, NH, dflag);
  }
  // 5. update (writes D2 into D buffers; D dead)
  k_update<<<(NH+255)/256, blk, 0, stream>>>(msg, Pi, Pa, Ps, b1, Di, Da, Ds, NH, dflag);
  // 6. node linears (W3) -> P2 (reuses P buffers)
  gemm(Di, 0, nullptr, 0, W3, 0,     nullptr, nullptr, Pi, N,   128, 128, 0, 0, 1);
  gemm(Da, 0, nullptr, 0, W3, 16384, nullptr, nullptr, Pa, 3*N, 128, 128, 0, 0, 1);
  gemm(Ds, 0, nullptr, 0, W3, 32768, nullptr, nullptr, Ps, 6*N, 128, 128, 0, 0, 1);
  // 7. final output
  k_final<<<(NH+255)/256, blk, 0, stream>>>(X, Pi, Pa, Ps, b3, d_out, NH, dflag);
}